// Round 1
// baseline (225.519 us; speedup 1.0000x reference)
//
#include <hip/hip_runtime.h>

#define B_  8
#define C_  256
#define C2_ 128
#define N_  4096
#define LOG2E 1.44269504088896f

typedef _Float16 f16;
typedef _Float16 f16x4 __attribute__((ext_vector_type(4)));
typedef _Float16 f16x8 __attribute__((ext_vector_type(8)));
typedef float f32x4  __attribute__((ext_vector_type(4)));

// ---------------------------------------------------------------------------
// prep: cast W1/W2 to f16 once (32768 elements each)
// ---------------------------------------------------------------------------
__global__ __launch_bounds__(256)
void prep_kernel(const float* __restrict__ W1, const float* __restrict__ W2,
                 f16* __restrict__ w1h, f16* __restrict__ w2h)
{
  int i = blockIdx.x * 256 + threadIdx.x;   // grid 128 -> 32768
  w1h[i] = (f16)W1[i];
  w2h[i] = (f16)W2[i];
}

// ---------------------------------------------------------------------------
// conv1: Y[b,n,c2] = sum_c x[b,c,n]*W1[c2,c] + b1; dual layout Y + Yt.
// (unchanged from verified baseline)
// ---------------------------------------------------------------------------
__global__ __launch_bounds__(256, 3)
void conv1_kernel(const float* __restrict__ x,
                  const f16* __restrict__ w1h,
                  const float* __restrict__ b1,
                  f16* __restrict__ Y, f16* __restrict__ Yt)
{
  __shared__ __align__(16) char smem[49152];
  float* Xr = (float*)smem;            // [256 c][32 n] f32, float4-block XOR (32 KB)
  f16*   Ah = (f16*)(smem + 32768);    // [32 n][256 k] f16 XOR-8 (16 KB)
  f16*   T  = (f16*)smem;              // [128 c2][40 n] epilogue alias

  const int t = threadIdx.x;
  const int w = t >> 6, lane = t & 63, quad = lane >> 4, l16 = lane & 15;
  const int b = blockIdx.x, nt0 = blockIdx.y;

  // stage all 256c x 32n fp32 (8 outstanding float4 loads)
#pragma unroll
  for (int pass = 0; pass < 8; pass++) {
    int c  = (t >> 3) + pass * 32;            // 0..255
    int n4 = t & 7;
    float4 v = *(const float4*)(x + ((long)(b * C_ + c)) * N_ + nt0 * 32 + n4 * 4);
    *(float4*)(&Xr[c * 32 + (n4 ^ (c & 7)) * 4]) = v;
  }
  __syncthreads();
  // transpose+cvt into Ah [n][k] XOR-8
#pragma unroll
  for (int pass = 0; pass < 4; pass++) {
    int n  = t & 31;
    int kb = (t >> 5) + pass * 8;             // 0..31
    f16x8 vh;
#pragma unroll
    for (int jj = 0; jj < 8; jj++) {
      int cc = kb * 8 + jj;
      vh[jj] = (f16)Xr[cc * 32 + ((n >> 2) ^ (cc & 7)) * 4 + (n & 3)];
    }
    *(f16x8*)(&Ah[n * 256 + (kb ^ (n & 7)) * 8]) = vh;
  }
  __syncthreads();

  // B-frags from global (L2-hot, shared by all WGs)
  f16x8 bh[2][8];
#pragma unroll
  for (int nt = 0; nt < 2; nt++) {
    int c2 = w * 32 + nt * 16 + l16;
#pragma unroll
    for (int ks = 0; ks < 8; ks++)
      bh[nt][ks] = *(const f16x8*)(w1h + c2 * C_ + ks * 32 + quad * 8);
  }

  f32x4 acc[2][2];
#pragma unroll
  for (int i = 0; i < 2; i++)
#pragma unroll
    for (int j = 0; j < 2; j++) acc[i][j] = (f32x4){0.f, 0.f, 0.f, 0.f};

#pragma unroll
  for (int ks = 0; ks < 8; ks++)
#pragma unroll
    for (int mt = 0; mt < 2; mt++) {
      f16x8 ah = *(const f16x8*)(&Ah[(mt * 16 + l16) * 256 + (((ks * 4 + quad) ^ (l16 & 7))) * 8]);
#pragma unroll
      for (int nt = 0; nt < 2; nt++)
        acc[mt][nt] = __builtin_amdgcn_mfma_f32_16x16x32_f16(ah, bh[nt][ks], acc[mt][nt], 0, 0, 0);
    }
  __syncthreads();   // Xr dead -> T alias safe

  // epilogue -> T[c2][n]
#pragma unroll
  for (int nt = 0; nt < 2; nt++) {
    int c2 = w * 32 + nt * 16 + l16;
    float bv = b1[c2];
#pragma unroll
    for (int mt = 0; mt < 2; mt++)
#pragma unroll
      for (int rg = 0; rg < 4; rg++) {
        int n = mt * 16 + quad * 4 + rg;
        T[c2 * 40 + n] = (f16)(acc[mt][nt][rg] + bv);
      }
  }
  __syncthreads();
  // Yt[c2][n]: vec8 along n
#pragma unroll
  for (int pass = 0; pass < 2; pass++) {
    int r  = (t >> 2) + pass * 64;            // c2 0..127
    int c8 = (t & 3) * 8;                     // n
    f16x8 v = *(const f16x8*)(&T[r * 40 + c8]);
    *(f16x8*)(Yt + ((long)(b * C2_ + r)) * N_ + nt0 * 32 + c8) = v;
  }
  // Y[n][c2]: gather
#pragma unroll
  for (int pass = 0; pass < 2; pass++) {
    int row = t & 31;
    int cg  = (t >> 5) + pass * 8;            // c2-block 0..15
    f16x8 v;
#pragma unroll
    for (int jj = 0; jj < 8; jj++) v[jj] = T[(cg * 8 + jj) * 40 + row];
    *(f16x8*)(Y + ((long)(b * N_ + nt0 * 32 + row)) * C2_ + cg * 8) = v;
  }
}

// ---------------------------------------------------------------------------
// attn v2: flash with FIXED per-row max = |y_q|^2 (unchanged math) but with
// IN-REGISTER P (T12-style swapped QK^T):
//   S^T = mfma_16x16x32(K_frag, Q_frag)  -> C layout row=key(quad*4+rg), col=q(l16)
//   which is EXACTLY the B-operand layout of mfma_f32_16x16x16f16, so the
//   exp'd P^T feeds PV directly from registers. Removes the Ps LDS buffer,
//   the 32 ds_write_u16 + 4 ds_read_b128 P round-trip per wave/tile, and the
//   scalar epilogue stores. PV: O^T += mfma16(V^T-frag[b64], P^T); l keeps
//   MFMA-exact consistency via mfma16(ones, P^T).
// BQ=128 (4 waves x 32 q), BK=64, split-K x2. Grid (8,32,2), LDS 32.5 KB.
// Outputs unnormalized O (f16, same [q][d] layout) + row sums l.
// ---------------------------------------------------------------------------
__global__ __launch_bounds__(256, 2)
void attn_kernel(const f16* __restrict__ Y, const f16* __restrict__ Yt,
                 f16* __restrict__ Op, float* __restrict__ ls)
{
  __shared__ f16 Ks[64 * 128];   // [key][d]  16B-block pos = (d>>3) ^ (key&15)
  __shared__ f16 Vs[128 * 64];   // [d][k]    pos = (k>>3) ^ (d&7)
  __shared__ float nsqf[128];

  const int t = threadIdx.x;
  const int w = t >> 6, lane = t & 63, quad = lane >> 4, l16 = lane & 15;
  const int b = blockIdx.x, qt = blockIdx.y, s = blockIdx.z;
  const f16* Yb  = Y  + (long)b * N_ * C2_;
  const f16* Ytb = Yt + (long)b * C2_ * N_;
  const int kbase0 = s * 2048;

  // Q frags: row q=l16, d-chunk quad*8 — valid as BOTH A- and B-operand of
  // 16x16x32 (identical per-lane maps), used as B below.
  f16x8 qf[2][4];
#pragma unroll
  for (int mt = 0; mt < 2; mt++)
#pragma unroll
    for (int ks = 0; ks < 4; ks++)
      qf[mt][ks] = *(const f16x8*)(Yb + (long)(qt * 128 + w * 32 + mt * 16 + l16) * C2_ + ks * 32 + quad * 8);

  // per-row |y_q|^2 (exact same f16 values the MFMA sees)
  {
    int r = t >> 1, half = t & 1;
    float ss = 0.f;
#pragma unroll
    for (int j = 0; j < 8; j++) {
      f16x8 v = *(const f16x8*)(Yb + (long)(qt * 128 + r) * C2_ + half * 64 + j * 8);
#pragma unroll
      for (int e = 0; e < 8; e++) { float f = (float)v[e]; ss = fmaf(f, f, ss); }
    }
    ss += __shfl_xor(ss, 1);
    if (!half) nsqf[r] = ss;
  }

  // prologue: stage tile 0 of this split
#pragma unroll
  for (int pass = 0; pass < 4; pass++) {
    int r = (t >> 4) + pass * 16;
    f16x8 kv = *(const f16x8*)(Yb + (long)(kbase0 + r) * C2_ + (t & 15) * 8);
    *(f16x8*)(&Ks[r * 128 + (((t & 15)) ^ (r & 15)) * 8]) = kv;
  }
#pragma unroll
  for (int pass = 0; pass < 4; pass++) {
    int d = (t >> 3) + pass * 32;
    f16x8 vv = *(const f16x8*)(Ytb + (long)d * N_ + kbase0 + (t & 7) * 8);
    *(f16x8*)(&Vs[d * 64 + (((t & 7)) ^ (d & 7)) * 8]) = vv;
  }
  __syncthreads();

  // fixed per-row max (log2 units), per-lane by q=l16
  float nm[2];
  nm[0] = nsqf[w * 32 + l16] * LOG2E;
  nm[1] = nsqf[w * 32 + 16 + l16] * LOG2E;

  const f16x4 ones4 = {(f16)1.f, (f16)1.f, (f16)1.f, (f16)1.f};

  f32x4 Oa[2][8];                 // O^T: [q-tile mt][d-tile dt], row=d_local, col=q
#pragma unroll
  for (int i = 0; i < 2; i++)
#pragma unroll
    for (int j = 0; j < 8; j++) Oa[i][j] = (f32x4){0.f, 0.f, 0.f, 0.f};
  f32x4 lac[2] = {(f32x4){0.f,0.f,0.f,0.f}, (f32x4){0.f,0.f,0.f,0.f}};

#pragma unroll 1
  for (int kt = 0; kt < 32; kt++) {
    // prefetch next tile into registers
    f16x8 stK[4], stV[4];
    if (kt + 1 < 32) {
      int nb = kbase0 + (kt + 1) * 64;
#pragma unroll
      for (int pass = 0; pass < 4; pass++)
        stK[pass] = *(const f16x8*)(Yb + (long)(nb + (t >> 4) + pass * 16) * C2_ + (t & 15) * 8);
#pragma unroll
      for (int pass = 0; pass < 4; pass++)
        stV[pass] = *(const f16x8*)(Ytb + (long)((t >> 3) + pass * 32) * N_ + nb + (t & 7) * 8);
    }

    // S^T = K Q^T (fp32): row = key(quad*4+rg within nt), col = q(l16 within mt)
    f32x4 S[4][2];
#pragma unroll
    for (int i = 0; i < 4; i++)
#pragma unroll
      for (int j = 0; j < 2; j++) S[i][j] = (f32x4){0.f, 0.f, 0.f, 0.f};
#pragma unroll
    for (int ks = 0; ks < 4; ks++) {
      f16x8 bfr[4];
#pragma unroll
      for (int nt = 0; nt < 4; nt++)
        bfr[nt] = *(const f16x8*)(&Ks[(nt * 16 + l16) * 128 + (((ks * 4 + quad) ^ l16)) * 8]);
#pragma unroll
      for (int nt = 0; nt < 4; nt++)
#pragma unroll
        for (int mt = 0; mt < 2; mt++)
          S[nt][mt] = __builtin_amdgcn_mfma_f32_16x16x32_f16(bfr[nt], qf[mt][ks], S[nt][mt], 0, 0, 0);
    }

    // fixed-max exp, P^T stays in registers (already in 16x16x16 B-frag layout)
    f16x4 pb[4][2];
#pragma unroll
    for (int nt = 0; nt < 4; nt++)
#pragma unroll
      for (int mt = 0; mt < 2; mt++) {
        f16x4 pv;
#pragma unroll
        for (int rg = 0; rg < 4; rg++)
          pv[rg] = (f16)exp2f(fminf(fmaf(S[nt][mt][rg], LOG2E, -nm[mt]), 11.0f));
        pb[nt][mt] = pv;
      }

    // l += colsum(P^T) via A=ones — consistent with the exact f16 P fed to PV
#pragma unroll
    for (int nt = 0; nt < 4; nt++)
#pragma unroll
      for (int mt = 0; mt < 2; mt++)
        lac[mt] = __builtin_amdgcn_mfma_f32_16x16x16f16(ones4, pb[nt][mt], lac[mt], 0, 0, 0);

    // O^T += V^T P^T : A = V^T [d16][k16] frags (b64 reads), B = pb (regs)
#pragma unroll
    for (int nt = 0; nt < 4; nt++) {
#pragma unroll
      for (int dt = 0; dt < 8; dt++) {
        f16x4 va = *(const f16x4*)(&Vs[(dt * 16 + l16) * 64
                      + (((nt * 2 + (quad >> 1)) ^ (l16 & 7))) * 8 + (quad & 1) * 4]);
#pragma unroll
        for (int mt = 0; mt < 2; mt++)
          Oa[mt][dt] = __builtin_amdgcn_mfma_f32_16x16x16f16(va, pb[nt][mt], Oa[mt][dt], 0, 0, 0);
      }
    }

    __syncthreads();   // all Ks/Vs reads done
    if (kt + 1 < 32) {
#pragma unroll
      for (int pass = 0; pass < 4; pass++) {
        int r = (t >> 4) + pass * 16;
        *(f16x8*)(&Ks[r * 128 + (((t & 15)) ^ (r & 15)) * 8]) = stK[pass];
      }
#pragma unroll
      for (int pass = 0; pass < 4; pass++) {
        int d = (t >> 3) + pass * 32;
        *(f16x8*)(&Vs[d * 64 + (((t & 7)) ^ (d & 7)) * 8]) = stV[pass];
      }
    }
    __syncthreads();
  }

  // epilogue: O^T regs -> Op[q][d] (packed 8B stores), l from any lac row
  const long rbase = ((long)s * B_ + b) * N_ + qt * 128;
#pragma unroll
  for (int mt = 0; mt < 2; mt++) {
    int q = w * 32 + mt * 16 + l16;
#pragma unroll
    for (int dt = 0; dt < 8; dt++) {
      f16x4 ov = {(f16)Oa[mt][dt][0], (f16)Oa[mt][dt][1],
                  (f16)Oa[mt][dt][2], (f16)Oa[mt][dt][3]};
      *(f16x4*)(Op + (rbase + q) * C2_ + dt * 16 + quad * 4) = ov;
    }
    if (quad == 0) ls[rbase + q] = lac[mt][0];
  }
}

// ---------------------------------------------------------------------------
// conv2 + fused split-combine + scale + residual (unchanged from baseline)
// ---------------------------------------------------------------------------
__global__ __launch_bounds__(256, 4)
void conv2_kernel(const f16* __restrict__ Op, const float* __restrict__ ls,
                  const f16* __restrict__ w2h,
                  const float* __restrict__ b2,
                  const float* __restrict__ scale,
                  const float* __restrict__ x,
                  float* __restrict__ out)
{
  __shared__ f16 Or[128 * 72];      // [j][p_local]
  __shared__ f16 Bsw[64 * 128];     // [p][j] XOR-16
  __shared__ float invL[128];

  const int t = threadIdx.x;
  const int w = t >> 6, lane = t & 63, quad = lane >> 4, l16 = lane & 15;
  const int b = blockIdx.x, pt = blockIdx.y, oh = blockIdx.z;
  const long base0 = (long)b * 524288;            // split 0, batch b
  const long base1 = 4194304 + base0;             // split 1

  if (t < 128) {
    int q = t * 32 + (pt >> 1);
    float l = ls[(long)b * N_ + q] + ls[32768 + (long)b * N_ + q];
    invL[t] = 1.0f / fmaxf(l, 1e-20f);
  }
  __syncthreads();

#pragma unroll
  for (int pass = 0; pass < 4; pass++) {
    int j = (t >> 3) + pass * 32;            // 0..127
    int c8 = (t & 7) * 8;                    // p_local
    f16x8 a0 = *(const f16x8*)(Op + base0 + (long)j * N_ + pt * 64 + c8);
    f16x8 a1 = *(const f16x8*)(Op + base1 + (long)j * N_ + pt * 64 + c8);
    float iv = invL[j];
    f16x8 r;
#pragma unroll
    for (int jj = 0; jj < 8; jj++)
      r[jj] = (f16)(((float)a0[jj] + (float)a1[jj]) * iv);
    *(f16x8*)(&Or[j * 72 + c8]) = r;
  }
  __syncthreads();
#pragma unroll
  for (int pass = 0; pass < 4; pass++) {
    int p = t & 63;
    int q = (t >> 6) + pass * 4;             // j-block 0..15
    f16x8 vv;
#pragma unroll
    for (int jj = 0; jj < 8; jj++) vv[jj] = Or[(q * 8 + jj) * 72 + p];
    *(f16x8*)(&Bsw[p * 128 + ((q ^ (p & 15))) * 8]) = vv;
  }
  __syncthreads();

  f32x4 acc[2][4];
#pragma unroll
  for (int i = 0; i < 2; i++)
#pragma unroll
    for (int j = 0; j < 4; j++) acc[i][j] = (f32x4){0.f, 0.f, 0.f, 0.f};

#pragma unroll
  for (int ks = 0; ks < 4; ks++) {
    f16x8 bfr[4];
#pragma unroll
    for (int nt = 0; nt < 4; nt++)
      bfr[nt] = *(const f16x8*)(&Bsw[(nt * 16 + l16) * 128 + (((ks * 4 + quad) ^ l16)) * 8]);
#pragma unroll
    for (int mt = 0; mt < 2; mt++) {
      int o = oh * 128 + w * 32 + mt * 16 + l16;
      f16x8 ah = *(const f16x8*)(w2h + o * C2_ + ks * 32 + quad * 8);
#pragma unroll
      for (int nt = 0; nt < 4; nt++)
        acc[mt][nt] = __builtin_amdgcn_mfma_f32_16x16x32_f16(ah, bfr[nt], acc[mt][nt], 0, 0, 0);
    }
  }
#pragma unroll
  for (int mt = 0; mt < 2; mt++)
#pragma unroll
    for (int rg = 0; rg < 4; rg++) {
      int o = oh * 128 + w * 32 + mt * 16 + quad * 4 + rg;
      float so = scale[o], bo = b2[o];
#pragma unroll
      for (int nt = 0; nt < 4; nt++) {
        int p = pt * 64 + nt * 16 + l16;
        long xo = ((long)b * C_ + o) * N_ + p;
        out[xo] = (acc[mt][nt][rg] + bo) * so + x[xo];
      }
    }
}

extern "C" void kernel_launch(void* const* d_in, const int* in_sizes, int n_in,
                              void* d_out, int out_size, void* d_ws, size_t ws_size,
                              hipStream_t stream) {
  const float* x     = (const float*)d_in[0];
  const float* W1    = (const float*)d_in[1];
  const float* b1    = (const float*)d_in[2];
  const float* W2    = (const float*)d_in[3];
  const float* b2    = (const float*)d_in[4];
  const float* scale = (const float*)d_in[5];
  float* outp = (float*)d_out;

  const size_t NE = (size_t)B_ * N_ * C2_;       // 4,194,304
  f16* Y   = (f16*)d_ws;                         // 8 MiB
  f16* Yt  = Y + NE;                             // 8 MiB
  f16* Op  = Yt + NE;                            // 2 splits x 8 MiB (unnormalized)
  float* ls = (float*)(Op + 2 * NE);             // 2 x 32768 f32 row sums
  f16* w1h = (f16*)(ls + 65536);
  f16* w2h = w1h + 32768;

  prep_kernel <<<dim3(128),      dim3(256), 0, stream>>>(W1, W2, w1h, w2h);
  conv1_kernel<<<dim3(8, 128),   dim3(256), 0, stream>>>(x, w1h, b1, Y, Yt);
  attn_kernel <<<dim3(8, 32, 2), dim3(256), 0, stream>>>(Y, Yt, Op, ls);
  conv2_kernel<<<dim3(8, 64, 2), dim3(256), 0, stream>>>(Op, ls, w2h, b2, scale, x, outp);
}

// Round 2
// 213.130 us; speedup vs baseline: 1.0581x; 1.0581x over previous
//
#include <hip/hip_runtime.h>

#define B_  8
#define C_  256
#define C2_ 128
#define N_  4096
#define LOG2E 1.44269504088896f

typedef _Float16 f16;
typedef _Float16 f16x2 __attribute__((ext_vector_type(2)));
typedef _Float16 f16x8 __attribute__((ext_vector_type(8)));
typedef float f32x4  __attribute__((ext_vector_type(4)));

static __device__ __forceinline__ unsigned pk2(float a, float b) {
  f16x2 h = {(f16)a, (f16)b};
  return __builtin_bit_cast(unsigned, h);
}

// ---------------------------------------------------------------------------
// prep: cast W1/W2 to f16 once (32768 elements each)
// ---------------------------------------------------------------------------
__global__ __launch_bounds__(256)
void prep_kernel(const float* __restrict__ W1, const float* __restrict__ W2,
                 f16* __restrict__ w1h, f16* __restrict__ w2h)
{
  int i = blockIdx.x * 256 + threadIdx.x;   // grid 128 -> 32768
  w1h[i] = (f16)W1[i];
  w2h[i] = (f16)W2[i];
}

// ---------------------------------------------------------------------------
// conv1: Y[b,n,c2] = sum_c x[b,c,n]*W1[c2,c] + b1; dual layout Y + Yt.
// (unchanged from verified baseline)
// ---------------------------------------------------------------------------
__global__ __launch_bounds__(256, 3)
void conv1_kernel(const float* __restrict__ x,
                  const f16* __restrict__ w1h,
                  const float* __restrict__ b1,
                  f16* __restrict__ Y, f16* __restrict__ Yt)
{
  __shared__ __align__(16) char smem[49152];
  float* Xr = (float*)smem;            // [256 c][32 n] f32, float4-block XOR (32 KB)
  f16*   Ah = (f16*)(smem + 32768);    // [32 n][256 k] f16 XOR-8 (16 KB)
  f16*   T  = (f16*)smem;              // [128 c2][40 n] epilogue alias

  const int t = threadIdx.x;
  const int w = t >> 6, lane = t & 63, quad = lane >> 4, l16 = lane & 15;
  const int b = blockIdx.x, nt0 = blockIdx.y;

  // stage all 256c x 32n fp32 (8 outstanding float4 loads)
#pragma unroll
  for (int pass = 0; pass < 8; pass++) {
    int c  = (t >> 3) + pass * 32;            // 0..255
    int n4 = t & 7;
    float4 v = *(const float4*)(x + ((long)(b * C_ + c)) * N_ + nt0 * 32 + n4 * 4);
    *(float4*)(&Xr[c * 32 + (n4 ^ (c & 7)) * 4]) = v;
  }
  __syncthreads();
  // transpose+cvt into Ah [n][k] XOR-8
#pragma unroll
  for (int pass = 0; pass < 4; pass++) {
    int n  = t & 31;
    int kb = (t >> 5) + pass * 8;             // 0..31
    f16x8 vh;
#pragma unroll
    for (int jj = 0; jj < 8; jj++) {
      int cc = kb * 8 + jj;
      vh[jj] = (f16)Xr[cc * 32 + ((n >> 2) ^ (cc & 7)) * 4 + (n & 3)];
    }
    *(f16x8*)(&Ah[n * 256 + (kb ^ (n & 7)) * 8]) = vh;
  }
  __syncthreads();

  // B-frags from global (L2-hot, shared by all WGs)
  f16x8 bh[2][8];
#pragma unroll
  for (int nt = 0; nt < 2; nt++) {
    int c2 = w * 32 + nt * 16 + l16;
#pragma unroll
    for (int ks = 0; ks < 8; ks++)
      bh[nt][ks] = *(const f16x8*)(w1h + c2 * C_ + ks * 32 + quad * 8);
  }

  f32x4 acc[2][2];
#pragma unroll
  for (int i = 0; i < 2; i++)
#pragma unroll
    for (int j = 0; j < 2; j++) acc[i][j] = (f32x4){0.f, 0.f, 0.f, 0.f};

#pragma unroll
  for (int ks = 0; ks < 8; ks++)
#pragma unroll
    for (int mt = 0; mt < 2; mt++) {
      f16x8 ah = *(const f16x8*)(&Ah[(mt * 16 + l16) * 256 + (((ks * 4 + quad) ^ (l16 & 7))) * 8]);
#pragma unroll
      for (int nt = 0; nt < 2; nt++)
        acc[mt][nt] = __builtin_amdgcn_mfma_f32_16x16x32_f16(ah, bh[nt][ks], acc[mt][nt], 0, 0, 0);
    }
  __syncthreads();   // Xr dead -> T alias safe

  // epilogue -> T[c2][n]
#pragma unroll
  for (int nt = 0; nt < 2; nt++) {
    int c2 = w * 32 + nt * 16 + l16;
    float bv = b1[c2];
#pragma unroll
    for (int mt = 0; mt < 2; mt++)
#pragma unroll
      for (int rg = 0; rg < 4; rg++) {
        int n = mt * 16 + quad * 4 + rg;
        T[c2 * 40 + n] = (f16)(acc[mt][nt][rg] + bv);
      }
  }
  __syncthreads();
  // Yt[c2][n]: vec8 along n
#pragma unroll
  for (int pass = 0; pass < 2; pass++) {
    int r  = (t >> 2) + pass * 64;            // c2 0..127
    int c8 = (t & 3) * 8;                     // n
    f16x8 v = *(const f16x8*)(&T[r * 40 + c8]);
    *(f16x8*)(Yt + ((long)(b * C2_ + r)) * N_ + nt0 * 32 + c8) = v;
  }
  // Y[n][c2]: gather
#pragma unroll
  for (int pass = 0; pass < 2; pass++) {
    int row = t & 31;
    int cg  = (t >> 5) + pass * 8;            // c2-block 0..15
    f16x8 v;
#pragma unroll
    for (int jj = 0; jj < 8; jj++) v[jj] = T[(cg * 8 + jj) * 40 + row];
    *(f16x8*)(Y + ((long)(b * N_ + nt0 * 32 + row)) * C2_ + cg * 8) = v;
  }
}

// ---------------------------------------------------------------------------
// attn v3: swapped QK^T (register P, verified R1) + BASELINE 16x16x32 PV.
// S^T C-layout gives lane(quad,l16): P[q=l16][key=nt*16+quad*4+rg].
// PV A-frag needs     lane(quad,l16): P[q=l16][k=ks2*32+quad*8+j].
// Same l16 column -> pure quad-level exchange:
//   1) v_permlane32_swap on (nt0,nt1)/(nt2,nt3) dword pairs:
//        lo = [Xa.r0, Xb.r0] (src quads 0,1), hi = [Xa.r1, Xb.r1] (quads 2,3)
//   2) ds_swizzle xor-16 + cndmask by quad parity assembles the 4 A-dwords.
// PV keeps baseline's conflict-free b128 vb reads + 36 16x16x32 MFMA/kt.
// No Ps buffer, no P LDS round-trip. LDS 32.5 KB. Grid (8,32,2).
// ---------------------------------------------------------------------------
__global__ __launch_bounds__(256, 2)
void attn_kernel(const f16* __restrict__ Y, const f16* __restrict__ Yt,
                 f16* __restrict__ Op, float* __restrict__ ls)
{
  __shared__ f16 Ks[64 * 128];   // [key][d]  16B-block pos = (d>>3) ^ (key&15)
  __shared__ f16 Vs[128 * 64];   // [d][k]    pos = (k>>3) ^ (d&7)
  __shared__ float nsqf[128];

  const int t = threadIdx.x;
  const int w = t >> 6, lane = t & 63, quad = lane >> 4, l16 = lane & 15;
  const int b = blockIdx.x, qt = blockIdx.y, s = blockIdx.z;
  const f16* Yb  = Y  + (long)b * N_ * C2_;
  const f16* Ytb = Yt + (long)b * C2_ * N_;
  const int kbase0 = s * 2048;

  // Q frags (A/B-frag layout identical for 16x16x32): row q=l16, d-chunk quad*8
  f16x8 qf[2][4];
#pragma unroll
  for (int mt = 0; mt < 2; mt++)
#pragma unroll
    for (int ks = 0; ks < 4; ks++)
      qf[mt][ks] = *(const f16x8*)(Yb + (long)(qt * 128 + w * 32 + mt * 16 + l16) * C2_ + ks * 32 + quad * 8);

  // per-row |y_q|^2 (exact same f16 values the MFMA sees)
  {
    int r = t >> 1, half = t & 1;
    float ss = 0.f;
#pragma unroll
    for (int j = 0; j < 8; j++) {
      f16x8 v = *(const f16x8*)(Yb + (long)(qt * 128 + r) * C2_ + half * 64 + j * 8);
#pragma unroll
      for (int e = 0; e < 8; e++) { float f = (float)v[e]; ss = fmaf(f, f, ss); }
    }
    ss += __shfl_xor(ss, 1);
    if (!half) nsqf[r] = ss;
  }

  // prologue: stage tile 0 of this split
#pragma unroll
  for (int pass = 0; pass < 4; pass++) {
    int r = (t >> 4) + pass * 16;
    f16x8 kv = *(const f16x8*)(Yb + (long)(kbase0 + r) * C2_ + (t & 15) * 8);
    *(f16x8*)(&Ks[r * 128 + (((t & 15)) ^ (r & 15)) * 8]) = kv;
  }
#pragma unroll
  for (int pass = 0; pass < 4; pass++) {
    int d = (t >> 3) + pass * 32;
    f16x8 vv = *(const f16x8*)(Ytb + (long)d * N_ + kbase0 + (t & 7) * 8);
    *(f16x8*)(&Vs[d * 64 + (((t & 7)) ^ (d & 7)) * 8]) = vv;
  }
  __syncthreads();

  // fixed per-row max (log2 units), per-lane by q=l16
  float nm[2];
  nm[0] = nsqf[w * 32 + l16] * LOG2E;
  nm[1] = nsqf[w * 32 + 16 + l16] * LOG2E;

  f16x8 ones8;
#pragma unroll
  for (int j = 0; j < 8; j++) ones8[j] = (f16)1.0f;

  f32x4 Oa[2][8];                 // C-layout: row q = quad*4+rg, col d = l16
#pragma unroll
  for (int i = 0; i < 2; i++)
#pragma unroll
    for (int j = 0; j < 8; j++) Oa[i][j] = (f32x4){0.f, 0.f, 0.f, 0.f};
  f32x4 lac[2] = {(f32x4){0.f,0.f,0.f,0.f}, (f32x4){0.f,0.f,0.f,0.f}};

#pragma unroll 1
  for (int kt = 0; kt < 32; kt++) {
    // prefetch next tile into registers
    f16x8 stK[4], stV[4];
    if (kt + 1 < 32) {
      int nb = kbase0 + (kt + 1) * 64;
#pragma unroll
      for (int pass = 0; pass < 4; pass++)
        stK[pass] = *(const f16x8*)(Yb + (long)(nb + (t >> 4) + pass * 16) * C2_ + (t & 15) * 8);
#pragma unroll
      for (int pass = 0; pass < 4; pass++)
        stV[pass] = *(const f16x8*)(Ytb + (long)((t >> 3) + pass * 32) * N_ + nb + (t & 7) * 8);
    }

    // S^T = K Q^T : row = key(quad*4+rg within nt), col = q(l16)
    f32x4 S[4][2];
#pragma unroll
    for (int i = 0; i < 4; i++)
#pragma unroll
      for (int j = 0; j < 2; j++) S[i][j] = (f32x4){0.f, 0.f, 0.f, 0.f};
#pragma unroll
    for (int ks = 0; ks < 4; ks++) {
      f16x8 bfr[4];
#pragma unroll
      for (int nt = 0; nt < 4; nt++)
        bfr[nt] = *(const f16x8*)(&Ks[(nt * 16 + l16) * 128 + (((ks * 4 + quad) ^ l16)) * 8]);
#pragma unroll
      for (int nt = 0; nt < 4; nt++)
#pragma unroll
        for (int mt = 0; mt < 2; mt++)
          S[nt][mt] = __builtin_amdgcn_mfma_f32_16x16x32_f16(bfr[nt], qf[mt][ks], S[nt][mt], 0, 0, 0);
    }

    // fixed-max exp -> packed f16 pairs: Xp[mt][nt][d] = keys quad*4+{2d,2d+1}
    unsigned Xp[2][4][2];
#pragma unroll
    for (int mt = 0; mt < 2; mt++)
#pragma unroll
      for (int nt = 0; nt < 4; nt++) {
        float p0 = exp2f(fminf(fmaf(S[nt][mt][0], LOG2E, -nm[mt]), 11.0f));
        float p1 = exp2f(fminf(fmaf(S[nt][mt][1], LOG2E, -nm[mt]), 11.0f));
        float p2 = exp2f(fminf(fmaf(S[nt][mt][2], LOG2E, -nm[mt]), 11.0f));
        float p3 = exp2f(fminf(fmaf(S[nt][mt][3], LOG2E, -nm[mt]), 11.0f));
        Xp[mt][nt][0] = pk2(p0, p1);
        Xp[mt][nt][1] = pk2(p2, p3);
      }

    // register exchange -> PV A-frags pa[ks2][mt] (P[q=l16][k=quad*8..+7])
    f16x8 pa[2][2];
    {
      const bool par = (quad & 1) != 0;
#pragma unroll
      for (int mt = 0; mt < 2; mt++) {
#pragma unroll
        for (int pr = 0; pr < 2; pr++)
#pragma unroll
          for (int d = 0; d < 2; d++) {
            auto r = __builtin_amdgcn_permlane32_swap(Xp[mt][2 * pr][d], Xp[mt][2 * pr + 1][d], false, false);
            Xp[mt][2 * pr][d]     = r[0];   // src quads 0,1 (nt pr*2 in lo half, pr*2+1 in hi half)
            Xp[mt][2 * pr + 1][d] = r[1];   // src quads 2,3
          }
#pragma unroll
        for (int ks2 = 0; ks2 < 2; ks2++) {
          unsigned lo0 = Xp[mt][2 * ks2][0],     lo1 = Xp[mt][2 * ks2][1];
          unsigned hi0 = Xp[mt][2 * ks2 + 1][0], hi1 = Xp[mt][2 * ks2 + 1][1];
          unsigned lo0x = (unsigned)__builtin_amdgcn_ds_swizzle((int)lo0, 0x401F);  // xor 16
          unsigned lo1x = (unsigned)__builtin_amdgcn_ds_swizzle((int)lo1, 0x401F);
          unsigned hi0x = (unsigned)__builtin_amdgcn_ds_swizzle((int)hi0, 0x401F);
          unsigned hi1x = (unsigned)__builtin_amdgcn_ds_swizzle((int)hi1, 0x401F);
          union { unsigned u[4]; f16x8 v; } P;
          P.u[0] = par ? hi0x : lo0;   // k quad*8 + {0,1}
          P.u[1] = par ? hi1x : lo1;   // + {2,3}
          P.u[2] = par ? hi0  : lo0x;  // + {4,5}
          P.u[3] = par ? hi1  : lo1x;  // + {6,7}
          pa[ks2][mt] = P.v;
        }
      }
    }

    // O += P V ; l += P 1  (baseline conflict-free 16x16x32 structure)
#pragma unroll
    for (int ks2 = 0; ks2 < 2; ks2++) {
      f16x8 vb[8];
#pragma unroll
      for (int dt = 0; dt < 8; dt++)
        vb[dt] = *(const f16x8*)(&Vs[(dt * 16 + l16) * 64 + (((ks2 * 4 + quad) ^ (l16 & 7))) * 8]);
#pragma unroll
      for (int mt = 0; mt < 2; mt++) {
#pragma unroll
        for (int dt = 0; dt < 8; dt++)
          Oa[mt][dt] = __builtin_amdgcn_mfma_f32_16x16x32_f16(pa[ks2][mt], vb[dt], Oa[mt][dt], 0, 0, 0);
        lac[mt] = __builtin_amdgcn_mfma_f32_16x16x32_f16(pa[ks2][mt], ones8, lac[mt], 0, 0, 0);
      }
    }

    __syncthreads();   // all Ks/Vs reads done
    if (kt + 1 < 32) {
#pragma unroll
      for (int pass = 0; pass < 4; pass++) {
        int r = (t >> 4) + pass * 16;
        *(f16x8*)(&Ks[r * 128 + (((t & 15)) ^ (r & 15)) * 8]) = stK[pass];
      }
#pragma unroll
      for (int pass = 0; pass < 4; pass++) {
        int d = (t >> 3) + pass * 32;
        *(f16x8*)(&Vs[d * 64 + (((t & 7)) ^ (d & 7)) * 8]) = stV[pass];
      }
    }
    __syncthreads();
  }

  // epilogue: unnormalized O + row sums l (baseline C-layout: row q, col d)
  const long rbase = ((long)s * B_ + b) * N_ + qt * 128;
#pragma unroll
  for (int mt = 0; mt < 2; mt++)
#pragma unroll
    for (int rg = 0; rg < 4; rg++) {
      int r = w * 32 + mt * 16 + quad * 4 + rg;
#pragma unroll
      for (int dt = 0; dt < 8; dt++)
        Op[(rbase + r) * C2_ + dt * 16 + l16] = (f16)Oa[mt][dt][rg];
      if (l16 == 0) ls[rbase + r] = lac[mt][rg];
    }
}

// ---------------------------------------------------------------------------
// conv2 + fused split-combine + scale + residual (unchanged from baseline)
// ---------------------------------------------------------------------------
__global__ __launch_bounds__(256, 4)
void conv2_kernel(const f16* __restrict__ Op, const float* __restrict__ ls,
                  const f16* __restrict__ w2h,
                  const float* __restrict__ b2,
                  const float* __restrict__ scale,
                  const float* __restrict__ x,
                  float* __restrict__ out)
{
  __shared__ f16 Or[128 * 72];      // [j][p_local]
  __shared__ f16 Bsw[64 * 128];     // [p][j] XOR-16
  __shared__ float invL[128];

  const int t = threadIdx.x;
  const int w = t >> 6, lane = t & 63, quad = lane >> 4, l16 = lane & 15;
  const int b = blockIdx.x, pt = blockIdx.y, oh = blockIdx.z;
  const long base0 = (long)b * 524288;            // split 0, batch b
  const long base1 = 4194304 + base0;             // split 1

  if (t < 128) {
    int q = t * 32 + (pt >> 1);
    float l = ls[(long)b * N_ + q] + ls[32768 + (long)b * N_ + q];
    invL[t] = 1.0f / fmaxf(l, 1e-20f);
  }
  __syncthreads();

#pragma unroll
  for (int pass = 0; pass < 4; pass++) {
    int j = (t >> 3) + pass * 32;            // 0..127
    int c8 = (t & 7) * 8;                    // p_local
    f16x8 a0 = *(const f16x8*)(Op + base0 + (long)j * N_ + pt * 64 + c8);
    f16x8 a1 = *(const f16x8*)(Op + base1 + (long)j * N_ + pt * 64 + c8);
    float iv = invL[j];
    f16x8 r;
#pragma unroll
    for (int jj = 0; jj < 8; jj++)
      r[jj] = (f16)(((float)a0[jj] + (float)a1[jj]) * iv);
    *(f16x8*)(&Or[j * 72 + c8]) = r;
  }
  __syncthreads();
#pragma unroll
  for (int pass = 0; pass < 4; pass++) {
    int p = t & 63;
    int q = (t >> 6) + pass * 4;             // j-block 0..15
    f16x8 vv;
#pragma unroll
    for (int jj = 0; jj < 8; jj++) vv[jj] = Or[(q * 8 + jj) * 72 + p];
    *(f16x8*)(&Bsw[p * 128 + ((q ^ (p & 15))) * 8]) = vv;
  }
  __syncthreads();

  f32x4 acc[2][4];
#pragma unroll
  for (int i = 0; i < 2; i++)
#pragma unroll
    for (int j = 0; j < 4; j++) acc[i][j] = (f32x4){0.f, 0.f, 0.f, 0.f};

#pragma unroll
  for (int ks = 0; ks < 4; ks++) {
    f16x8 bfr[4];
#pragma unroll
    for (int nt = 0; nt < 4; nt++)
      bfr[nt] = *(const f16x8*)(&Bsw[(nt * 16 + l16) * 128 + (((ks * 4 + quad) ^ l16)) * 8]);
#pragma unroll
    for (int mt = 0; mt < 2; mt++) {
      int o = oh * 128 + w * 32 + mt * 16 + l16;
      f16x8 ah = *(const f16x8*)(w2h + o * C2_ + ks * 32 + quad * 8);
#pragma unroll
      for (int nt = 0; nt < 4; nt++)
        acc[mt][nt] = __builtin_amdgcn_mfma_f32_16x16x32_f16(ah, bfr[nt], acc[mt][nt], 0, 0, 0);
    }
  }
#pragma unroll
  for (int mt = 0; mt < 2; mt++)
#pragma unroll
    for (int rg = 0; rg < 4; rg++) {
      int o = oh * 128 + w * 32 + mt * 16 + quad * 4 + rg;
      float so = scale[o], bo = b2[o];
#pragma unroll
      for (int nt = 0; nt < 4; nt++) {
        int p = pt * 64 + nt * 16 + l16;
        long xo = ((long)b * C_ + o) * N_ + p;
        out[xo] = (acc[mt][nt][rg] + bo) * so + x[xo];
      }
    }
}

extern "C" void kernel_launch(void* const* d_in, const int* in_sizes, int n_in,
                              void* d_out, int out_size, void* d_ws, size_t ws_size,
                              hipStream_t stream) {
  const float* x     = (const float*)d_in[0];
  const float* W1    = (const float*)d_in[1];
  const float* b1    = (const float*)d_in[2];
  const float* W2    = (const float*)d_in[3];
  const float* b2    = (const float*)d_in[4];
  const float* scale = (const float*)d_in[5];
  float* outp = (float*)d_out;

  const size_t NE = (size_t)B_ * N_ * C2_;       // 4,194,304
  f16* Y   = (f16*)d_ws;                         // 8 MiB
  f16* Yt  = Y + NE;                             // 8 MiB
  f16* Op  = Yt + NE;                            // 2 splits x 8 MiB (unnormalized)
  float* ls = (float*)(Op + 2 * NE);             // 2 x 32768 f32 row sums
  f16* w1h = (f16*)(ls + 65536);
  f16* w2h = w1h + 32768;

  prep_kernel <<<dim3(128),      dim3(256), 0, stream>>>(W1, W2, w1h, w2h);
  conv1_kernel<<<dim3(8, 128),   dim3(256), 0, stream>>>(x, w1h, b1, Y, Yt);
  attn_kernel <<<dim3(8, 32, 2), dim3(256), 0, stream>>>(Y, Yt, Op, ls);
  conv2_kernel<<<dim3(8, 64, 2), dim3(256), 0, stream>>>(Op, ls, w2h, b2, scale, x, outp);
}